// Round 1
// baseline (38297.833 us; speedup 1.0000x reference)
//
#include <hip/hip_runtime.h>
#include <math.h>

#define T_STEPS 4096
#define HID     2048
#define MOD     256
#define INSZ    1024
#define NB_REC  64
#define TPB_REC 256

// ---------------------------------------------------------------------------
// Agent-scope (device) coherent helpers — cross-XCD L2s are not coherent, so
// all cross-step shared data (h values living in `out`) goes through these.
// ---------------------------------------------------------------------------
static __device__ __forceinline__ float agent_load_f(const float* p) {
    return __hip_atomic_load((float*)p, __ATOMIC_RELAXED, __HIP_MEMORY_SCOPE_AGENT);
}
static __device__ __forceinline__ void agent_store_f(float* p, float v) {
    __hip_atomic_store(p, v, __ATOMIC_RELAXED, __HIP_MEMORY_SCOPE_AGENT);
}

// ---------------------------------------------------------------------------
// Kernel 1: U = x @ W_ih^T + (b_ih + b_hh), written into out[t, i].
// Classic 128x128 tile, BK=8, 256 threads, 8x8 per thread, fp32.
// ---------------------------------------------------------------------------
#define BM 128
#define BN 128
#define BK 8

__global__ __launch_bounds__(256) void gemm_u(
    const float* __restrict__ x, const float* __restrict__ Wih,
    const float* __restrict__ bih, const float* __restrict__ bhh,
    float* __restrict__ out)
{
    __shared__ float As[BK][BM];
    __shared__ float Bs[BK][BN];

    const int tid = threadIdx.x;
    const int t0 = blockIdx.y * BM;   // time-block
    const int i0 = blockIdx.x * BN;   // hidden-block
    const int tx = tid & 15;          // col group (i)
    const int ty = tid >> 4;          // row group (t)

    const int arow = tid >> 1;            // 0..127
    const int acol = (tid & 1) * 4;       // 0 or 4

    float acc[8][8];
#pragma unroll
    for (int a = 0; a < 8; ++a)
#pragma unroll
        for (int b = 0; b < 8; ++b) acc[a][b] = 0.0f;

    for (int k0 = 0; k0 < INSZ; k0 += BK) {
        float4 av = *(const float4*)(x   + (size_t)(t0 + arow) * INSZ + k0 + acol);
        float4 bv = *(const float4*)(Wih + (size_t)(i0 + arow) * INSZ + k0 + acol);
        __syncthreads();   // previous tile fully consumed
        As[acol + 0][arow] = av.x; As[acol + 1][arow] = av.y;
        As[acol + 2][arow] = av.z; As[acol + 3][arow] = av.w;
        Bs[acol + 0][arow] = bv.x; Bs[acol + 1][arow] = bv.y;
        Bs[acol + 2][arow] = bv.z; Bs[acol + 3][arow] = bv.w;
        __syncthreads();
#pragma unroll
        for (int kk = 0; kk < BK; ++kk) {
            float a[8], b[8];
            *(float4*)&a[0] = *(const float4*)&As[kk][ty * 8];
            *(float4*)&a[4] = *(const float4*)&As[kk][ty * 8 + 4];
            *(float4*)&b[0] = *(const float4*)&Bs[kk][tx * 8];
            *(float4*)&b[4] = *(const float4*)&Bs[kk][tx * 8 + 4];
#pragma unroll
            for (int ri = 0; ri < 8; ++ri)
#pragma unroll
                for (int ci = 0; ci < 8; ++ci)
                    acc[ri][ci] = fmaf(a[ri], b[ci], acc[ri][ci]);
        }
    }

    float bias[8];
#pragma unroll
    for (int ci = 0; ci < 8; ++ci) {
        int i = i0 + tx * 8 + ci;
        bias[ci] = bih[i] + bhh[i];
    }
#pragma unroll
    for (int ri = 0; ri < 8; ++ri) {
        int t = t0 + ty * 8 + ri;
#pragma unroll
        for (int ci = 0; ci < 8; ++ci) {
            int i = i0 + tx * 8 + ci;
            out[(size_t)t * HID + i] = acc[ri][ci] + bias[ci];
        }
    }
}

// ---------------------------------------------------------------------------
// Kernel 2: persistent recurrence. 64 blocks x 256 threads, one global
// generation barrier per step. h(t) lives in out[t-1] (overwrites U in place).
// LDS keeps h(t-1); only the prefix that changed at step t-1 is re-loaded.
// ---------------------------------------------------------------------------
__global__ __launch_bounds__(TPB_REC) void cwrnn_rec(
    float* __restrict__ out, const float* __restrict__ Whh, unsigned* bar)
{
    __shared__ float hs[HID];
    const int tid   = threadIdx.x;
    const int lane  = tid & 63;
    const int wid   = tid >> 6;                 // 0..3
    const int gwave = blockIdx.x * 4 + wid;     // 0..255
    unsigned* cnt = bar;
    unsigned* gen = bar + 1;

    for (int t = 1; t <= T_STEPS; ++t) {
        // --- refresh LDS copy of h(t-1): only rows active at step t-1 changed
        if (t == 1) {
            for (int k = tid; k < HID; k += TPB_REC) hs[k] = 0.0f;
        } else {
            int Ap = __builtin_ctz(t - 1) + 1; if (Ap > 8) Ap = 8;
            int Rp = Ap * MOD;                  // rows updated at step t-1
            const float* hp = out + (size_t)(t - 2) * HID;
            for (int k = tid; k < Rp; k += TPB_REC)
                hs[k] = agent_load_f(hp + k);
        }
        __syncthreads();

        int A = __builtin_ctz(t) + 1; if (A > 8) A = 8;
        int R = A * MOD;                        // active rows this step
        float* orow = out + (size_t)(t - 1) * HID;

        // --- active rows: one wave per row, dot(W_hh[r,:], h(t-1))
        for (int r = gwave; r < R; r += NB_REC * 4) {
            const float4* wrow = (const float4*)(Whh + (size_t)r * HID);
            const float4* h4   = (const float4*)hs;
            float acc = 0.0f;
#pragma unroll
            for (int j = 0; j < HID / 4 / 64; ++j) {    // 8 iters
                float4 w = wrow[lane + 64 * j];
                float4 h = h4[lane + 64 * j];
                acc = fmaf(w.x, h.x, fmaf(w.y, h.y,
                      fmaf(w.z, h.z, fmaf(w.w, h.w, acc))));
            }
#pragma unroll
            for (int off = 32; off; off >>= 1)
                acc += __shfl_xor(acc, off, 64);
            if (lane == 0) {
                float u = agent_load_f(orow + r);       // U (includes biases)
                agent_store_f(orow + r, tanhf(u + acc));
            }
        }

        // --- inactive rows: out[t-1, k] = h(t-1)[k]
        for (int k = R + blockIdx.x * TPB_REC + tid; k < HID; k += NB_REC * TPB_REC)
            agent_store_f(orow + k, hs[k]);

        // --- grid barrier (generation = t)
        __syncthreads();
        if (tid == 0) {
            __threadfence();
            unsigned a = __hip_atomic_fetch_add(cnt, 1u, __ATOMIC_ACQ_REL,
                                                __HIP_MEMORY_SCOPE_AGENT);
            if (a == NB_REC - 1) {
                __hip_atomic_store(cnt, 0u, __ATOMIC_RELAXED, __HIP_MEMORY_SCOPE_AGENT);
                __hip_atomic_store(gen, (unsigned)t, __ATOMIC_RELEASE,
                                   __HIP_MEMORY_SCOPE_AGENT);
            } else {
                while (__hip_atomic_load(gen, __ATOMIC_ACQUIRE,
                                         __HIP_MEMORY_SCOPE_AGENT) < (unsigned)t)
                    __builtin_amdgcn_s_sleep(2);
            }
            __threadfence();
        }
        __syncthreads();
    }
}

// ---------------------------------------------------------------------------
extern "C" void kernel_launch(void* const* d_in, const int* in_sizes, int n_in,
                              void* d_out, int out_size, void* d_ws, size_t ws_size,
                              hipStream_t stream) {
    const float* x   = (const float*)d_in[0];
    const float* Wih = (const float*)d_in[1];
    const float* Whh = (const float*)d_in[2];
    const float* bih = (const float*)d_in[3];
    const float* bhh = (const float*)d_in[4];
    float* out = (float*)d_out;
    unsigned* bar = (unsigned*)d_ws;

    // barrier state (cnt, gen) must be zero every call (ws is re-poisoned)
    hipMemsetAsync(d_ws, 0, 256, stream);

    dim3 g1(HID / BN, T_STEPS / BM);     // (16, 32)
    gemm_u<<<g1, 256, 0, stream>>>(x, Wih, bih, bhh, out);
    cwrnn_rec<<<NB_REC, TPB_REC, 0, stream>>>(out, Whh, bar);
}

// Round 2
// 24925.465 us; speedup vs baseline: 1.5365x; 1.5365x over previous
//
#include <hip/hip_runtime.h>
#include <math.h>

#define T_STEPS 4096
#define HID     2048
#define MOD     256
#define INSZ    1024
#define NB_REC  16
#define TPB_REC 1024
#define WPB     (TPB_REC / 64)        // 16 waves per block
#define GWAVES  (NB_REC * WPB)        // 256 global waves == module-0 rows

// ---------------------------------------------------------------------------
// Agent-scope (device-coherent, sc1) helpers. All cross-step shared data goes
// through these; they bypass L1/L2 staleness so NO fences are needed.
// ---------------------------------------------------------------------------
static __device__ __forceinline__ float agent_load_f(const float* p) {
    return __hip_atomic_load((float*)p, __ATOMIC_RELAXED, __HIP_MEMORY_SCOPE_AGENT);
}
static __device__ __forceinline__ void agent_store_f(float* p, float v) {
    __hip_atomic_store(p, v, __ATOMIC_RELAXED, __HIP_MEMORY_SCOPE_AGENT);
}

// ---------------------------------------------------------------------------
// Kernel 1: U = x @ W_ih^T + (b_ih + b_hh), written into out[t, i].
// 128x128 tile, BK=8, 256 threads, 8x8 per thread, fp32.
// ---------------------------------------------------------------------------
#define BM 128
#define BN 128
#define BK 8

__global__ __launch_bounds__(256) void gemm_u(
    const float* __restrict__ x, const float* __restrict__ Wih,
    const float* __restrict__ bih, const float* __restrict__ bhh,
    float* __restrict__ out)
{
    __shared__ float As[BK][BM];
    __shared__ float Bs[BK][BN];

    const int tid = threadIdx.x;
    const int t0 = blockIdx.y * BM;
    const int i0 = blockIdx.x * BN;
    const int tx = tid & 15;
    const int ty = tid >> 4;
    const int arow = tid >> 1;
    const int acol = (tid & 1) * 4;

    float acc[8][8];
#pragma unroll
    for (int a = 0; a < 8; ++a)
#pragma unroll
        for (int b = 0; b < 8; ++b) acc[a][b] = 0.0f;

    for (int k0 = 0; k0 < INSZ; k0 += BK) {
        float4 av = *(const float4*)(x   + (size_t)(t0 + arow) * INSZ + k0 + acol);
        float4 bv = *(const float4*)(Wih + (size_t)(i0 + arow) * INSZ + k0 + acol);
        __syncthreads();
        As[acol + 0][arow] = av.x; As[acol + 1][arow] = av.y;
        As[acol + 2][arow] = av.z; As[acol + 3][arow] = av.w;
        Bs[acol + 0][arow] = bv.x; Bs[acol + 1][arow] = bv.y;
        Bs[acol + 2][arow] = bv.z; Bs[acol + 3][arow] = bv.w;
        __syncthreads();
#pragma unroll
        for (int kk = 0; kk < BK; ++kk) {
            float a[8], b[8];
            *(float4*)&a[0] = *(const float4*)&As[kk][ty * 8];
            *(float4*)&a[4] = *(const float4*)&As[kk][ty * 8 + 4];
            *(float4*)&b[0] = *(const float4*)&Bs[kk][tx * 8];
            *(float4*)&b[4] = *(const float4*)&Bs[kk][tx * 8 + 4];
#pragma unroll
            for (int ri = 0; ri < 8; ++ri)
#pragma unroll
                for (int ci = 0; ci < 8; ++ci)
                    acc[ri][ci] = fmaf(a[ri], b[ci], acc[ri][ci]);
        }
    }

    float bias[8];
#pragma unroll
    for (int ci = 0; ci < 8; ++ci) {
        int i = i0 + tx * 8 + ci;
        bias[ci] = bih[i] + bhh[i];
    }
#pragma unroll
    for (int ri = 0; ri < 8; ++ri) {
        int t = t0 + ty * 8 + ri;
#pragma unroll
        for (int ci = 0; ci < 8; ++ci) {
            int i = i0 + tx * 8 + ci;
            out[(size_t)t * HID + i] = acc[ri][ci] + bias[ci];
        }
    }
}

// ---------------------------------------------------------------------------
// Kernel 2: persistent recurrence. 16 blocks x 1024 threads (256 waves).
// Wave g owns module-0 row g, with W_hh[g,:] cached in 32 VGPRs.
// Monotonic-counter barrier: RELEASE arrival, RELAXED spin, no fences.
// ---------------------------------------------------------------------------
__global__ __launch_bounds__(TPB_REC) void cwrnn_rec(
    float* __restrict__ out, const float* __restrict__ Whh, unsigned* bar)
{
    __shared__ float hs[HID];
    const int tid   = threadIdx.x;
    const int lane  = tid & 63;
    const int wid   = tid >> 6;
    const int gwave = blockIdx.x * WPB + wid;   // 0..255 == owned module-0 row
    unsigned* done = bar;

    // Cache W_hh[gwave, :] : lane holds float4s at cols 4*lane + 256*j
    float4 w0[8];
    {
        const float4* wr = (const float4*)(Whh + (size_t)gwave * HID);
#pragma unroll
        for (int j = 0; j < 8; ++j) w0[j] = wr[lane + 64 * j];
    }

    for (int t = 1; t <= T_STEPS; ++t) {
        // --- refresh LDS h(t-1): only the prefix active at step t-1 changed
        if (t == 1) {
            for (int k = tid; k < HID; k += TPB_REC) hs[k] = 0.0f;
        } else {
            int Ap = __builtin_ctz(t - 1) + 1; if (Ap > 8) Ap = 8;
            int Rp = Ap * MOD;
            const float* hp = out + (size_t)(t - 2) * HID;
            for (int k = tid; k < Rp; k += TPB_REC)
                hs[k] = agent_load_f(hp + k);
        }
        __syncthreads();

        const int A = (__builtin_ctz(t) + 1 > 8) ? 8 : (__builtin_ctz(t) + 1);
        const int R = A * MOD;
        float* orow = out + (size_t)(t - 1) * HID;
        const float4* h4 = (const float4*)hs;

        // --- owned module-0 row (register-cached W, every step)
        {
            float acc = 0.0f;
#pragma unroll
            for (int j = 0; j < 8; ++j) {
                float4 h = h4[lane + 64 * j];
                acc = fmaf(w0[j].x, h.x, fmaf(w0[j].y, h.y,
                      fmaf(w0[j].z, h.z, fmaf(w0[j].w, h.w, acc))));
            }
#pragma unroll
            for (int off = 32; off; off >>= 1) acc += __shfl_xor(acc, off, 64);
            if (lane == 0) {
                float u = orow[gwave];              // U: plain load (fresh region)
                agent_store_f(orow + gwave, tanhf(u + acc));
            }
        }

        // --- streamed rows (modules 1..A-1), pairs share one h read
        int m = 1;
        for (; m + 1 < A; m += 2) {
            const int ra = m * MOD + gwave;
            const int rb = ra + MOD;
            const float4* wa = (const float4*)(Whh + (size_t)ra * HID);
            const float4* wb = (const float4*)(Whh + (size_t)rb * HID);
            float acca = 0.0f, accb = 0.0f;
#pragma unroll
            for (int j = 0; j < 8; ++j) {
                float4 h = h4[lane + 64 * j];
                float4 a = wa[lane + 64 * j];
                float4 b = wb[lane + 64 * j];
                acca = fmaf(a.x, h.x, fmaf(a.y, h.y,
                       fmaf(a.z, h.z, fmaf(a.w, h.w, acca))));
                accb = fmaf(b.x, h.x, fmaf(b.y, h.y,
                       fmaf(b.z, h.z, fmaf(b.w, h.w, accb))));
            }
#pragma unroll
            for (int off = 32; off; off >>= 1) {
                acca += __shfl_xor(acca, off, 64);
                accb += __shfl_xor(accb, off, 64);
            }
            if (lane == 0) {
                agent_store_f(orow + ra, tanhf(orow[ra] + acca));
                agent_store_f(orow + rb, tanhf(orow[rb] + accb));
            }
        }
        if (m < A) {                                 // tail single row
            const int r = m * MOD + gwave;
            const float4* wr = (const float4*)(Whh + (size_t)r * HID);
            float acc = 0.0f;
#pragma unroll
            for (int j = 0; j < 8; ++j) {
                float4 h = h4[lane + 64 * j];
                float4 a = wr[lane + 64 * j];
                acc = fmaf(a.x, h.x, fmaf(a.y, h.y,
                      fmaf(a.z, h.z, fmaf(a.w, h.w, acc))));
            }
#pragma unroll
            for (int off = 32; off; off >>= 1) acc += __shfl_xor(acc, off, 64);
            if (lane == 0)
                agent_store_f(orow + r, tanhf(orow[r] + acc));
        }

        // --- inactive rows: plain streaming store (nobody reads cross-step)
        for (int k = R + blockIdx.x * TPB_REC + tid; k < HID; k += NB_REC * TPB_REC)
            orow[k] = hs[k];

        // --- monotonic barrier: arrive(RELEASE) then relaxed spin
        __syncthreads();   // all waves' stores drained (vmcnt0 before s_barrier)
        if (tid == 0) {
            __hip_atomic_fetch_add(done, 1u, __ATOMIC_RELEASE,
                                   __HIP_MEMORY_SCOPE_AGENT);
            const unsigned target = (unsigned)NB_REC * (unsigned)t;
            while (__hip_atomic_load(done, __ATOMIC_RELAXED,
                                     __HIP_MEMORY_SCOPE_AGENT) < target)
                __builtin_amdgcn_s_sleep(1);
        }
        __syncthreads();
    }
}

// ---------------------------------------------------------------------------
extern "C" void kernel_launch(void* const* d_in, const int* in_sizes, int n_in,
                              void* d_out, int out_size, void* d_ws, size_t ws_size,
                              hipStream_t stream) {
    const float* x   = (const float*)d_in[0];
    const float* Wih = (const float*)d_in[1];
    const float* Whh = (const float*)d_in[2];
    const float* bih = (const float*)d_in[3];
    const float* bhh = (const float*)d_in[4];
    float* out = (float*)d_out;
    unsigned* bar = (unsigned*)d_ws;

    hipMemsetAsync(d_ws, 0, 256, stream);   // barrier counter must start at 0

    dim3 g1(HID / BN, T_STEPS / BM);        // (16, 32)
    gemm_u<<<g1, 256, 0, stream>>>(x, Wih, bih, bhh, out);
    cwrnn_rec<<<NB_REC, TPB_REC, 0, stream>>>(out, Whh, bar);
}

// Round 3
// 14789.967 us; speedup vs baseline: 2.5894x; 1.6853x over previous
//
#include <hip/hip_runtime.h>
#include <math.h>

#define T_STEPS 4096
#define HID     2048
#define MOD     256
#define INSZ    1024
#define NB_REC  16
#define TPB_REC 1024
#define WPB     (TPB_REC / 64)        // 16 waves per block
#define SLOT_STRIDE 16                // 16 dwords = 64 B between arrival slots

// ---------------------------------------------------------------------------
// Agent-scope (device-coherent, sc1) helpers. All cross-step shared data goes
// through these; they are serviced at the coherence point (LLC), bypassing
// the non-coherent per-XCD L2s, so no fences / cache maintenance needed.
// ---------------------------------------------------------------------------
static __device__ __forceinline__ float agent_load_f(const float* p) {
    return __hip_atomic_load((float*)p, __ATOMIC_RELAXED, __HIP_MEMORY_SCOPE_AGENT);
}
static __device__ __forceinline__ void agent_store_f(float* p, float v) {
    __hip_atomic_store(p, v, __ATOMIC_RELAXED, __HIP_MEMORY_SCOPE_AGENT);
}
static __device__ __forceinline__ unsigned agent_load_u(const unsigned* p) {
    return __hip_atomic_load((unsigned*)p, __ATOMIC_RELAXED, __HIP_MEMORY_SCOPE_AGENT);
}
static __device__ __forceinline__ void agent_store_u(unsigned* p, unsigned v) {
    __hip_atomic_store(p, v, __ATOMIC_RELAXED, __HIP_MEMORY_SCOPE_AGENT);
}

// ---------------------------------------------------------------------------
// Kernel 1: U = x @ W_ih^T + (b_ih + b_hh), written into out[t, i].
// 128x128 tile, BK=8, 256 threads, 8x8 per thread, fp32. (~0.2 ms, fine.)
// ---------------------------------------------------------------------------
#define BM 128
#define BN 128
#define BK 8

__global__ __launch_bounds__(256) void gemm_u(
    const float* __restrict__ x, const float* __restrict__ Wih,
    const float* __restrict__ bih, const float* __restrict__ bhh,
    float* __restrict__ out)
{
    __shared__ float As[BK][BM];
    __shared__ float Bs[BK][BN];

    const int tid = threadIdx.x;
    const int t0 = blockIdx.y * BM;
    const int i0 = blockIdx.x * BN;
    const int tx = tid & 15;
    const int ty = tid >> 4;
    const int arow = tid >> 1;
    const int acol = (tid & 1) * 4;

    float acc[8][8];
#pragma unroll
    for (int a = 0; a < 8; ++a)
#pragma unroll
        for (int b = 0; b < 8; ++b) acc[a][b] = 0.0f;

    for (int k0 = 0; k0 < INSZ; k0 += BK) {
        float4 av = *(const float4*)(x   + (size_t)(t0 + arow) * INSZ + k0 + acol);
        float4 bv = *(const float4*)(Wih + (size_t)(i0 + arow) * INSZ + k0 + acol);
        __syncthreads();
        As[acol + 0][arow] = av.x; As[acol + 1][arow] = av.y;
        As[acol + 2][arow] = av.z; As[acol + 3][arow] = av.w;
        Bs[acol + 0][arow] = bv.x; Bs[acol + 1][arow] = bv.y;
        Bs[acol + 2][arow] = bv.z; Bs[acol + 3][arow] = bv.w;
        __syncthreads();
#pragma unroll
        for (int kk = 0; kk < BK; ++kk) {
            float a[8], b[8];
            *(float4*)&a[0] = *(const float4*)&As[kk][ty * 8];
            *(float4*)&a[4] = *(const float4*)&As[kk][ty * 8 + 4];
            *(float4*)&b[0] = *(const float4*)&Bs[kk][tx * 8];
            *(float4*)&b[4] = *(const float4*)&Bs[kk][tx * 8 + 4];
#pragma unroll
            for (int ri = 0; ri < 8; ++ri)
#pragma unroll
                for (int ci = 0; ci < 8; ++ci)
                    acc[ri][ci] = fmaf(a[ri], b[ci], acc[ri][ci]);
        }
    }

    float bias[8];
#pragma unroll
    for (int ci = 0; ci < 8; ++ci) {
        int i = i0 + tx * 8 + ci;
        bias[ci] = bih[i] + bhh[i];
    }
#pragma unroll
    for (int ri = 0; ri < 8; ++ri) {
        int t = t0 + ty * 8 + ri;
#pragma unroll
        for (int ci = 0; ci < 8; ++ci) {
            int i = i0 + tx * 8 + ci;
            out[(size_t)t * HID + i] = acc[ri][ci] + bias[ci];
        }
    }
}

// ---------------------------------------------------------------------------
// Kernel 2: persistent recurrence. 16 blocks x 1024 threads (256 waves).
// Barrier = per-block arrival slots (relaxed sc1 store, 64B apart) + parallel
// 16-lane poll. No atomic RMW, no release/acquire cache maintenance.
// Inactive-row stores deferred past the flag (nobody reads them cross-step).
// ---------------------------------------------------------------------------
__global__ __launch_bounds__(TPB_REC) void cwrnn_rec(
    float* __restrict__ out, const float* __restrict__ Whh, unsigned* slots)
{
    __shared__ float hs[HID];
    const int tid   = threadIdx.x;
    const int lane  = tid & 63;
    const int wid   = tid >> 6;
    const int gwave = blockIdx.x * WPB + wid;   // 0..255 == owned module-0 row

    // Cache W_hh[gwave, :] : lane holds float4s at cols 4*lane + 256*j
    float4 w0[8];
    {
        const float4* wr = (const float4*)(Whh + (size_t)gwave * HID);
#pragma unroll
        for (int j = 0; j < 8; ++j) w0[j] = wr[lane + 64 * j];
    }

    for (int t = 1; t <= T_STEPS; ++t) {
        // --- refresh LDS h(t-1): only the prefix active at step t-1 changed.
        // (Gated by previous iteration's bottom __syncthreads -> flag detect.)
        if (t == 1) {
            for (int k = tid; k < HID; k += TPB_REC) hs[k] = 0.0f;
        } else {
            int Ap = __builtin_ctz(t - 1) + 1; if (Ap > 8) Ap = 8;
            int Rp = Ap * MOD;
            const float* hp = out + (size_t)(t - 2) * HID;
            for (int k = tid; k < Rp; k += TPB_REC)
                hs[k] = agent_load_f(hp + k);
        }
        __syncthreads();

        const int A = (__builtin_ctz(t) + 1 > 8) ? 8 : (__builtin_ctz(t) + 1);
        const int R = A * MOD;
        float* orow = out + (size_t)(t - 1) * HID;
        const float4* h4 = (const float4*)hs;

        // --- U prefetch: lane m (< A) grabs U for row m*256+gwave (plain load,
        // GEMM wrote it; this row of `out` isn't overwritten until now).
        float upf = 0.0f;
        if (lane < A) upf = orow[lane * MOD + gwave];

        // --- owned module-0 row (register-cached W, every step)
        {
            float acc = 0.0f;
#pragma unroll
            for (int j = 0; j < 8; ++j) {
                float4 h = h4[lane + 64 * j];
                acc = fmaf(w0[j].x, h.x, fmaf(w0[j].y, h.y,
                      fmaf(w0[j].z, h.z, fmaf(w0[j].w, h.w, acc))));
            }
#pragma unroll
            for (int off = 32; off; off >>= 1) acc += __shfl_xor(acc, off, 64);
            float u0 = __shfl(upf, 0, 64);
            if (lane == 0)
                agent_store_f(orow + gwave, tanhf(u0 + acc));
        }

        // --- streamed rows (modules 1..A-1), pairs share one h read
        int m = 1;
        for (; m + 1 < A; m += 2) {
            const int ra = m * MOD + gwave;
            const int rb = ra + MOD;
            const float4* wa = (const float4*)(Whh + (size_t)ra * HID);
            const float4* wb = (const float4*)(Whh + (size_t)rb * HID);
            float acca = 0.0f, accb = 0.0f;
#pragma unroll
            for (int j = 0; j < 8; ++j) {
                float4 h = h4[lane + 64 * j];
                float4 a = wa[lane + 64 * j];
                float4 b = wb[lane + 64 * j];
                acca = fmaf(a.x, h.x, fmaf(a.y, h.y,
                       fmaf(a.z, h.z, fmaf(a.w, h.w, acca))));
                accb = fmaf(b.x, h.x, fmaf(b.y, h.y,
                       fmaf(b.z, h.z, fmaf(b.w, h.w, accb))));
            }
#pragma unroll
            for (int off = 32; off; off >>= 1) {
                acca += __shfl_xor(acca, off, 64);
                accb += __shfl_xor(accb, off, 64);
            }
            float ua = __shfl(upf, m, 64);
            float ub = __shfl(upf, m + 1, 64);
            if (lane == 0) {
                agent_store_f(orow + ra, tanhf(ua + acca));
                agent_store_f(orow + rb, tanhf(ub + accb));
            }
        }
        if (m < A) {                                 // tail single row
            const int r = m * MOD + gwave;
            const float4* wr = (const float4*)(Whh + (size_t)r * HID);
            float acc = 0.0f;
#pragma unroll
            for (int j = 0; j < 8; ++j) {
                float4 h = h4[lane + 64 * j];
                float4 a = wr[lane + 64 * j];
                acc = fmaf(a.x, h.x, fmaf(a.y, h.y,
                      fmaf(a.z, h.z, fmaf(a.w, h.w, acc))));
            }
#pragma unroll
            for (int off = 32; off; off >>= 1) acc += __shfl_xor(acc, off, 64);
            float um = __shfl(upf, m, 64);
            if (lane == 0)
                agent_store_f(orow + r, tanhf(um + acc));
        }

        // --- arrival: __syncthreads drains the agent stores (vmcnt(0) before
        // s_barrier), so a plain relaxed flag store suffices for visibility.
        __syncthreads();
        if (tid == 0)
            agent_store_u(slots + blockIdx.x * SLOT_STRIDE, (unsigned)t);

        // --- deferred inactive rows: plain streaming store, only the harness
        // reads them (refresh reads just the active prefix). Overlaps poll.
        for (int k = R + blockIdx.x * TPB_REC + tid; k < HID; k += NB_REC * TPB_REC)
            orow[k] = hs[k];

        // --- detect: lanes 0..15 of wave 0 poll all slots in parallel
        if (wid == 0) {
            for (;;) {
                unsigned v = 0xFFFFFFFFu;
                if (lane < NB_REC)
                    v = agent_load_u(slots + lane * SLOT_STRIDE);
                if (__all(v >= (unsigned)t)) break;
                __builtin_amdgcn_s_sleep(1);
            }
        }
        __syncthreads();   // gates next iteration's hs refresh on detection
    }
}

// ---------------------------------------------------------------------------
extern "C" void kernel_launch(void* const* d_in, const int* in_sizes, int n_in,
                              void* d_out, int out_size, void* d_ws, size_t ws_size,
                              hipStream_t stream) {
    const float* x   = (const float*)d_in[0];
    const float* Wih = (const float*)d_in[1];
    const float* Whh = (const float*)d_in[2];
    const float* bih = (const float*)d_in[3];
    const float* bhh = (const float*)d_in[4];
    float* out = (float*)d_out;
    unsigned* slots = (unsigned*)d_ws;

    // arrival slots must start at 0 (t goes 1..4096)
    hipMemsetAsync(d_ws, 0, NB_REC * SLOT_STRIDE * sizeof(unsigned), stream);

    dim3 g1(HID / BN, T_STEPS / BM);        // (16, 32)
    gemm_u<<<g1, 256, 0, stream>>>(x, Wih, bih, bhh, out);
    cwrnn_rec<<<NB_REC, TPB_REC, 0, stream>>>(out, Whh, slots);
}

// Round 4
// 13850.832 us; speedup vs baseline: 2.7650x; 1.0678x over previous
//
#include <hip/hip_runtime.h>
#include <math.h>

#define T_STEPS 4096
#define HID     2048
#define MOD     256
#define INSZ    1024
#define NB_REC  16
#define TPB_REC 1024
#define WPB     (TPB_REC / 64)        // 16 waves per block

// ---------------------------------------------------------------------------
// Agent-scope (device-coherent, sc1) helpers — serviced at the coherence
// point (LLC), bypassing the non-coherent per-XCD L2s. Relaxed: no cache
// maintenance, no fences.
// ---------------------------------------------------------------------------
static __device__ __forceinline__ unsigned long long agent_load_u64(
        const unsigned long long* p) {
    return __hip_atomic_load((unsigned long long*)p, __ATOMIC_RELAXED,
                             __HIP_MEMORY_SCOPE_AGENT);
}
static __device__ __forceinline__ void agent_store_u64(
        unsigned long long* p, unsigned long long v) {
    __hip_atomic_store(p, v, __ATOMIC_RELAXED, __HIP_MEMORY_SCOPE_AGENT);
}

// ---------------------------------------------------------------------------
// Kernel 1: U = x @ W_ih^T + (b_ih + b_hh), written into out[t, i].
// 128x128 tile, BK=8, 256 threads, 8x8 per thread, fp32.
// ---------------------------------------------------------------------------
#define BM 128
#define BN 128
#define BK 8

__global__ __launch_bounds__(256) void gemm_u(
    const float* __restrict__ x, const float* __restrict__ Wih,
    const float* __restrict__ bih, const float* __restrict__ bhh,
    float* __restrict__ out)
{
    __shared__ float As[BK][BM];
    __shared__ float Bs[BK][BN];

    const int tid = threadIdx.x;
    const int t0 = blockIdx.y * BM;
    const int i0 = blockIdx.x * BN;
    const int tx = tid & 15;
    const int ty = tid >> 4;
    const int arow = tid >> 1;
    const int acol = (tid & 1) * 4;

    float acc[8][8];
#pragma unroll
    for (int a = 0; a < 8; ++a)
#pragma unroll
        for (int b = 0; b < 8; ++b) acc[a][b] = 0.0f;

    for (int k0 = 0; k0 < INSZ; k0 += BK) {
        float4 av = *(const float4*)(x   + (size_t)(t0 + arow) * INSZ + k0 + acol);
        float4 bv = *(const float4*)(Wih + (size_t)(i0 + arow) * INSZ + k0 + acol);
        __syncthreads();
        As[acol + 0][arow] = av.x; As[acol + 1][arow] = av.y;
        As[acol + 2][arow] = av.z; As[acol + 3][arow] = av.w;
        Bs[acol + 0][arow] = bv.x; Bs[acol + 1][arow] = bv.y;
        Bs[acol + 2][arow] = bv.z; Bs[acol + 3][arow] = bv.w;
        __syncthreads();
#pragma unroll
        for (int kk = 0; kk < BK; ++kk) {
            float a[8], b[8];
            *(float4*)&a[0] = *(const float4*)&As[kk][ty * 8];
            *(float4*)&a[4] = *(const float4*)&As[kk][ty * 8 + 4];
            *(float4*)&b[0] = *(const float4*)&Bs[kk][tx * 8];
            *(float4*)&b[4] = *(const float4*)&Bs[kk][tx * 8 + 4];
#pragma unroll
            for (int ri = 0; ri < 8; ++ri)
#pragma unroll
                for (int ci = 0; ci < 8; ++ci)
                    acc[ri][ci] = fmaf(a[ri], b[ci], acc[ri][ci]);
        }
    }

    float bias[8];
#pragma unroll
    for (int ci = 0; ci < 8; ++ci) {
        int i = i0 + tx * 8 + ci;
        bias[ci] = bih[i] + bhh[i];
    }
#pragma unroll
    for (int ri = 0; ri < 8; ++ri) {
        int t = t0 + ty * 8 + ri;
#pragma unroll
        for (int ci = 0; ci < 8; ++ci) {
            int i = i0 + tx * 8 + ci;
            out[(size_t)t * HID + i] = acc[ri][ci] + bias[ci];
        }
    }
}

// ---------------------------------------------------------------------------
// Kernel 2: persistent recurrence, flagless. h values are published as
// self-validating (tag<<32 | bits) packets in comm[parity][r]; consumers
// poll the packet itself — data+flag in one LLC round trip. 2-deep parity
// buffering is safe: writing tag t+1 requires having observed all tag-t
// rows, which each block publishes only after its refresh (which read the
// tag-(t-1) slots) passed __syncthreads. `out` is never read cross-block:
// plain cached stores only, inactive fill deferred to overlap the next poll.
// ---------------------------------------------------------------------------
__global__ __launch_bounds__(TPB_REC) void cwrnn_rec(
    float* __restrict__ out, const float* __restrict__ Whh,
    unsigned long long* __restrict__ comm)
{
    __shared__ float hs[HID];
    const int tid   = threadIdx.x;
    const int lane  = tid & 63;
    const int wid   = tid >> 6;
    const int gwave = blockIdx.x * WPB + wid;   // 0..255 == owned module-0 row

    // Cache W_hh[gwave, :] in 32 VGPRs (lane holds cols 4*lane + 256*j)
    float4 w0[8];
    {
        const float4* wr = (const float4*)(Whh + (size_t)gwave * HID);
#pragma unroll
        for (int j = 0; j < 8; ++j) w0[j] = wr[lane + 64 * j];
    }

    for (int k = tid; k < HID; k += TPB_REC) hs[k] = 0.0f;   // h(0) = 0

    int Rprev = HID;   // t=1: no refresh, no deferred fill
    for (int t = 1; t <= T_STEPS; ++t) {
        if (t > 1) {
            // deferred inactive fill for step t-1: out[t-2][k]=hs[k], k>=Rprev
            // (reads hs[k>=Rprev], disjoint from refresh writes hs[k<Rprev])
            float* prow = out + (size_t)(t - 2) * HID;
            for (int k = Rprev + blockIdx.x * TPB_REC + tid; k < HID;
                 k += NB_REC * TPB_REC)
                prow[k] = hs[k];

            // refresh: poll self-validating packets for rows active at t-1
            const unsigned long long* csrc = comm + (size_t)((t - 1) & 1) * HID;
            const unsigned need = (unsigned)(t - 1);
            for (int k = tid; k < Rprev; k += TPB_REC) {
                unsigned long long v = agent_load_u64(csrc + k);
                while ((unsigned)(v >> 32) < need)
                    v = agent_load_u64(csrc + k);
                hs[k] = __uint_as_float((unsigned)v);
            }
        }
        __syncthreads();

        const int A = (__builtin_ctz(t) + 1 > 8) ? 8 : (__builtin_ctz(t) + 1);
        const int R = A * MOD;
        float* orow = out + (size_t)(t - 1) * HID;
        const float4* h4 = (const float4*)hs;
        unsigned long long* cdst = comm + (size_t)(t & 1) * HID;
        const unsigned long long tagbits = ((unsigned long long)(unsigned)t) << 32;

        // U prefetch: lane m (< A) grabs U for row m*256+gwave (GEMM output)
        float upf = 0.0f;
        if (lane < A) upf = orow[lane * MOD + gwave];

        // --- owned module-0 row (register-cached W, every step)
        {
            float acc = 0.0f;
#pragma unroll
            for (int j = 0; j < 8; ++j) {
                float4 h = h4[lane + 64 * j];
                acc = fmaf(w0[j].x, h.x, fmaf(w0[j].y, h.y,
                      fmaf(w0[j].z, h.z, fmaf(w0[j].w, h.w, acc))));
            }
#pragma unroll
            for (int off = 32; off; off >>= 1) acc += __shfl_xor(acc, off, 64);
            float u0 = __shfl(upf, 0, 64);
            if (lane == 0) {
                float hv = tanhf(u0 + acc);
                agent_store_u64(cdst + gwave,
                    tagbits | (unsigned long long)__float_as_uint(hv));
                orow[gwave] = hv;
            }
        }

        // --- streamed rows (modules 1..A-1), pairs share one h read
        int m = 1;
        for (; m + 1 < A; m += 2) {
            const int ra = m * MOD + gwave;
            const int rb = ra + MOD;
            const float4* wa = (const float4*)(Whh + (size_t)ra * HID);
            const float4* wb = (const float4*)(Whh + (size_t)rb * HID);
            float acca = 0.0f, accb = 0.0f;
#pragma unroll
            for (int j = 0; j < 8; ++j) {
                float4 h = h4[lane + 64 * j];
                float4 a = wa[lane + 64 * j];
                float4 b = wb[lane + 64 * j];
                acca = fmaf(a.x, h.x, fmaf(a.y, h.y,
                       fmaf(a.z, h.z, fmaf(a.w, h.w, acca))));
                accb = fmaf(b.x, h.x, fmaf(b.y, h.y,
                       fmaf(b.z, h.z, fmaf(b.w, h.w, accb))));
            }
#pragma unroll
            for (int off = 32; off; off >>= 1) {
                acca += __shfl_xor(acca, off, 64);
                accb += __shfl_xor(accb, off, 64);
            }
            float ua = __shfl(upf, m, 64);
            float ub = __shfl(upf, m + 1, 64);
            if (lane == 0) {
                float hva = tanhf(ua + acca);
                float hvb = tanhf(ub + accb);
                agent_store_u64(cdst + ra,
                    tagbits | (unsigned long long)__float_as_uint(hva));
                agent_store_u64(cdst + rb,
                    tagbits | (unsigned long long)__float_as_uint(hvb));
                orow[ra] = hva;
                orow[rb] = hvb;
            }
        }
        if (m < A) {                                 // tail single row
            const int r = m * MOD + gwave;
            const float4* wr = (const float4*)(Whh + (size_t)r * HID);
            float acc = 0.0f;
#pragma unroll
            for (int j = 0; j < 8; ++j) {
                float4 h = h4[lane + 64 * j];
                float4 a = wr[lane + 64 * j];
                acc = fmaf(a.x, h.x, fmaf(a.y, h.y,
                      fmaf(a.z, h.z, fmaf(a.w, h.w, acc))));
            }
#pragma unroll
            for (int off = 32; off; off >>= 1) acc += __shfl_xor(acc, off, 64);
            float um = __shfl(upf, m, 64);
            if (lane == 0) {
                float hv = tanhf(um + acc);
                agent_store_u64(cdst + r,
                    tagbits | (unsigned long long)__float_as_uint(hv));
                orow[r] = hv;
            }
        }

        __syncthreads();   // hs read-stability vs next iteration's refresh
        Rprev = R;
    }

    // final inactive fill for t=4096 (R(4096)=2048 -> empty, kept for safety)
    {
        float* prow = out + (size_t)(T_STEPS - 1) * HID;
        for (int k = Rprev + blockIdx.x * TPB_REC + tid; k < HID;
             k += NB_REC * TPB_REC)
            prow[k] = hs[k];
    }
}

// ---------------------------------------------------------------------------
extern "C" void kernel_launch(void* const* d_in, const int* in_sizes, int n_in,
                              void* d_out, int out_size, void* d_ws, size_t ws_size,
                              hipStream_t stream) {
    const float* x   = (const float*)d_in[0];
    const float* Wih = (const float*)d_in[1];
    const float* Whh = (const float*)d_in[2];
    const float* bih = (const float*)d_in[3];
    const float* bhh = (const float*)d_in[4];
    float* out = (float*)d_out;
    unsigned long long* comm = (unsigned long long*)d_ws;

    // comm tags must start at 0 (t goes 1..4096): 2 parities x 2048 x 8B
    hipMemsetAsync(d_ws, 0, 2 * HID * sizeof(unsigned long long), stream);

    dim3 g1(HID / BN, T_STEPS / BM);        // (16, 32)
    gemm_u<<<g1, 256, 0, stream>>>(x, Wih, bih, bhh, out);
    cwrnn_rec<<<NB_REC, TPB_REC, 0, stream>>>(out, Whh, comm);
}

// Round 5
// 11199.296 us; speedup vs baseline: 3.4197x; 1.2368x over previous
//
#include <hip/hip_runtime.h>
#include <math.h>

#define T_STEPS 4096
#define HID     2048
#define MOD     256
#define INSZ    1024
#define NWAVE   256            // one wave per block, one block per CU

// ---------------------------------------------------------------------------
// Agent-scope (device-coherent, sc1) helpers — serviced at the coherence
// point (LLC), bypassing the non-coherent per-XCD L2s. Relaxed: no cache
// maintenance, no fences.
// ---------------------------------------------------------------------------
static __device__ __forceinline__ unsigned long long agent_load_u64(
        const unsigned long long* p) {
    return __hip_atomic_load((unsigned long long*)p, __ATOMIC_RELAXED,
                             __HIP_MEMORY_SCOPE_AGENT);
}
static __device__ __forceinline__ void agent_store_u64(
        unsigned long long* p, unsigned long long v) {
    __hip_atomic_store(p, v, __ATOMIC_RELAXED, __HIP_MEMORY_SCOPE_AGENT);
}

// ---------------------------------------------------------------------------
// Kernel 1: U = x @ W_ih^T + (b_ih + b_hh), written into out[t, i].
// 128x128 tile, BK=8, 256 threads, 8x8 per thread, fp32.
// ---------------------------------------------------------------------------
#define BM 128
#define BN 128
#define BK 8

__global__ __launch_bounds__(256) void gemm_u(
    const float* __restrict__ x, const float* __restrict__ Wih,
    const float* __restrict__ bih, const float* __restrict__ bhh,
    float* __restrict__ out)
{
    __shared__ float As[BK][BM];
    __shared__ float Bs[BK][BN];

    const int tid = threadIdx.x;
    const int t0 = blockIdx.y * BM;
    const int i0 = blockIdx.x * BN;
    const int tx = tid & 15;
    const int ty = tid >> 4;
    const int arow = tid >> 1;
    const int acol = (tid & 1) * 4;

    float acc[8][8];
#pragma unroll
    for (int a = 0; a < 8; ++a)
#pragma unroll
        for (int b = 0; b < 8; ++b) acc[a][b] = 0.0f;

    for (int k0 = 0; k0 < INSZ; k0 += BK) {
        float4 av = *(const float4*)(x   + (size_t)(t0 + arow) * INSZ + k0 + acol);
        float4 bv = *(const float4*)(Wih + (size_t)(i0 + arow) * INSZ + k0 + acol);
        __syncthreads();
        As[acol + 0][arow] = av.x; As[acol + 1][arow] = av.y;
        As[acol + 2][arow] = av.z; As[acol + 3][arow] = av.w;
        Bs[acol + 0][arow] = bv.x; Bs[acol + 1][arow] = bv.y;
        Bs[acol + 2][arow] = bv.z; Bs[acol + 3][arow] = bv.w;
        __syncthreads();
#pragma unroll
        for (int kk = 0; kk < BK; ++kk) {
            float a[8], b[8];
            *(float4*)&a[0] = *(const float4*)&As[kk][ty * 8];
            *(float4*)&a[4] = *(const float4*)&As[kk][ty * 8 + 4];
            *(float4*)&b[0] = *(const float4*)&Bs[kk][tx * 8];
            *(float4*)&b[4] = *(const float4*)&Bs[kk][tx * 8 + 4];
#pragma unroll
            for (int ri = 0; ri < 8; ++ri)
#pragma unroll
                for (int ci = 0; ci < 8; ++ci)
                    acc[ri][ci] = fmaf(a[ri], b[ci], acc[ri][ci]);
        }
    }

    float bias[8];
#pragma unroll
    for (int ci = 0; ci < 8; ++ci) {
        int i = i0 + tx * 8 + ci;
        bias[ci] = bih[i] + bhh[i];
    }
#pragma unroll
    for (int ri = 0; ri < 8; ++ri) {
        int t = t0 + ty * 8 + ri;
#pragma unroll
        for (int ci = 0; ci < 8; ++ci) {
            int i = i0 + tx * 8 + ci;
            out[(size_t)t * HID + i] = acc[ri][ci] + bias[ci];
        }
    }
}

// ---------------------------------------------------------------------------
// Kernel 2: persistent recurrence, barrier-free. 256 blocks x 64 threads
// (one wave per CU). Each wave keeps the FULL h in registers (lane l holds
// cols 256j+4l..+3, j=0..7) plus its owned module-0 W row. Cross-wave
// exchange = self-validating (tag<<32|bits) packets in comm[parity][col];
// the poll IS the data load (1 LLC round trip). Parity reuse is safe by
// induction: publishing t requires having consumed all tag-(t-1) module-0
// packets (true data dependency through the dot), so no wave can overwrite
// a parity slot while any other wave still needs it.
// ---------------------------------------------------------------------------
__global__ __launch_bounds__(64, 1) void cwrnn_rec(
    float* __restrict__ out, const float* __restrict__ Whh,
    unsigned long long* __restrict__ comm)
{
    const int lane = threadIdx.x;        // 0..63
    const int g    = blockIdx.x;         // wave id 0..255 == owned module-0 row

    // register h(0) = 0 : hreg[j] = h[256j + 4*lane .. +3]
    float4 hreg[8];
#pragma unroll
    for (int j = 0; j < 8; ++j) hreg[j] = make_float4(0.f, 0.f, 0.f, 0.f);

    // cache W_hh[g, :] with matching fragment layout: w0[j] = W[g][256j+4l..+3]
    float4 w0[8];
    {
        const float4* wr = (const float4*)(Whh + (size_t)g * HID);
#pragma unroll
        for (int j = 0; j < 8; ++j) w0[j] = wr[lane + 64 * j];
    }

    for (int t = 1; t <= T_STEPS; ++t) {
        const int ctz = __builtin_ctz(t);
        const int A = (ctz + 1 > 8) ? 8 : (ctz + 1);
        float* orow = out + (size_t)(t - 1) * HID;

        // U prefetch: lane m (< A) grabs U for row m*256+g (gemm output,
        // this wave's own columns only — no cross-wave plain-memory sharing)
        float upf = (lane < A) ? orow[lane * MOD + g] : 0.0f;

        // --- refresh register-h prefix: poll all packets in ONE retry loop
        if (t > 1) {
            const int ctzp = __builtin_ctz(t - 1);
            const int Ap = (ctzp + 1 > 8) ? 8 : (ctzp + 1);
            const unsigned need = (unsigned)(t - 1);
            const unsigned long long* csrc =
                comm + (size_t)((t - 1) & 1) * HID + 4 * lane;
            unsigned long long pv[8][4];
            for (;;) {
                // issue every load back-to-back (1 round trip), then check
#pragma unroll
                for (int j = 0; j < 8; ++j) {
                    if (j < Ap) {
                        pv[j][0] = agent_load_u64(csrc + j * MOD + 0);
                        pv[j][1] = agent_load_u64(csrc + j * MOD + 1);
                        pv[j][2] = agent_load_u64(csrc + j * MOD + 2);
                        pv[j][3] = agent_load_u64(csrc + j * MOD + 3);
                    }
                }
                bool ok = true;
#pragma unroll
                for (int j = 0; j < 8; ++j) {
                    if (j < Ap)
                        ok = ok && ((unsigned)(pv[j][0] >> 32) >= need)
                                && ((unsigned)(pv[j][1] >> 32) >= need)
                                && ((unsigned)(pv[j][2] >> 32) >= need)
                                && ((unsigned)(pv[j][3] >> 32) >= need);
                }
                if (ok) break;
            }
#pragma unroll
            for (int j = 0; j < 8; ++j) {
                if (j < Ap)
                    hreg[j] = make_float4(
                        __uint_as_float((unsigned)pv[j][0]),
                        __uint_as_float((unsigned)pv[j][1]),
                        __uint_as_float((unsigned)pv[j][2]),
                        __uint_as_float((unsigned)pv[j][3]));
            }
        }

        unsigned long long* cdst = comm + (size_t)(t & 1) * HID;
        const unsigned long long tagbits =
            ((unsigned long long)(unsigned)t) << 32;

        // --- owned module-0 row: all-register dot (4-lane-partials, short chain)
        {
            float4 s = make_float4(0.f, 0.f, 0.f, 0.f);
#pragma unroll
            for (int j = 0; j < 8; ++j) {
                s.x = fmaf(w0[j].x, hreg[j].x, s.x);
                s.y = fmaf(w0[j].y, hreg[j].y, s.y);
                s.z = fmaf(w0[j].z, hreg[j].z, s.z);
                s.w = fmaf(w0[j].w, hreg[j].w, s.w);
            }
            float acc = (s.x + s.y) + (s.z + s.w);
#pragma unroll
            for (int off = 32; off; off >>= 1) acc += __shfl_xor(acc, off, 64);
            float u0 = __shfl(upf, 0, 64);
            if (lane == 0) {
                float hv = tanhf(u0 + acc);
                agent_store_u64(cdst + g,
                    tagbits | (unsigned long long)__float_as_uint(hv));
                orow[g] = hv;
            }
        }

        // --- streamed rows (modules 1..A-1), pairs for load-level parallelism
        int m = 1;
        for (; m + 1 < A; m += 2) {
            const int ra = m * MOD + g;
            const int rb = ra + MOD;
            const float4* wa = (const float4*)(Whh + (size_t)ra * HID);
            const float4* wb = (const float4*)(Whh + (size_t)rb * HID);
            float4 sa = make_float4(0.f, 0.f, 0.f, 0.f);
            float4 sb = make_float4(0.f, 0.f, 0.f, 0.f);
#pragma unroll
            for (int j = 0; j < 8; ++j) {
                float4 a = wa[lane + 64 * j];
                float4 b = wb[lane + 64 * j];
                sa.x = fmaf(a.x, hreg[j].x, sa.x);
                sa.y = fmaf(a.y, hreg[j].y, sa.y);
                sa.z = fmaf(a.z, hreg[j].z, sa.z);
                sa.w = fmaf(a.w, hreg[j].w, sa.w);
                sb.x = fmaf(b.x, hreg[j].x, sb.x);
                sb.y = fmaf(b.y, hreg[j].y, sb.y);
                sb.z = fmaf(b.z, hreg[j].z, sb.z);
                sb.w = fmaf(b.w, hreg[j].w, sb.w);
            }
            float acca = (sa.x + sa.y) + (sa.z + sa.w);
            float accb = (sb.x + sb.y) + (sb.z + sb.w);
#pragma unroll
            for (int off = 32; off; off >>= 1) {
                acca += __shfl_xor(acca, off, 64);
                accb += __shfl_xor(accb, off, 64);
            }
            float ua = __shfl(upf, m, 64);
            float ub = __shfl(upf, m + 1, 64);
            if (lane == 0) {
                float hva = tanhf(ua + acca);
                float hvb = tanhf(ub + accb);
                agent_store_u64(cdst + ra,
                    tagbits | (unsigned long long)__float_as_uint(hva));
                agent_store_u64(cdst + rb,
                    tagbits | (unsigned long long)__float_as_uint(hvb));
                orow[ra] = hva;
                orow[rb] = hvb;
            }
        }
        if (m < A) {                                 // tail single row
            const int r = m * MOD + g;
            const float4* wr = (const float4*)(Whh + (size_t)r * HID);
            float4 s = make_float4(0.f, 0.f, 0.f, 0.f);
#pragma unroll
            for (int j = 0; j < 8; ++j) {
                float4 a = wr[lane + 64 * j];
                s.x = fmaf(a.x, hreg[j].x, s.x);
                s.y = fmaf(a.y, hreg[j].y, s.y);
                s.z = fmaf(a.z, hreg[j].z, s.z);
                s.w = fmaf(a.w, hreg[j].w, s.w);
            }
            float acc = (s.x + s.y) + (s.z + s.w);
#pragma unroll
            for (int off = 32; off; off >>= 1) acc += __shfl_xor(acc, off, 64);
            float um = __shfl(upf, m, 64);
            if (lane == 0) {
                float hv = tanhf(um + acc);
                agent_store_u64(cdst + r,
                    tagbits | (unsigned long long)__float_as_uint(hv));
                orow[r] = hv;
            }
        }

        // --- inactive rows: wave (j - A) writes module j from its registers
        // (hreg == h(t-1) == h(t) on inactive modules). Plain cached stores;
        // only the harness reads them.
#pragma unroll
        for (int j = 0; j < 8; ++j) {
            if (j >= A && g == (j - A)) {
                *(float4*)(orow + j * MOD + 4 * lane) = hreg[j];
            }
        }
    }
}

// ---------------------------------------------------------------------------
extern "C" void kernel_launch(void* const* d_in, const int* in_sizes, int n_in,
                              void* d_out, int out_size, void* d_ws, size_t ws_size,
                              hipStream_t stream) {
    const float* x   = (const float*)d_in[0];
    const float* Wih = (const float*)d_in[1];
    const float* Whh = (const float*)d_in[2];
    const float* bih = (const float*)d_in[3];
    const float* bhh = (const float*)d_in[4];
    float* out = (float*)d_out;
    unsigned long long* comm = (unsigned long long*)d_ws;

    // comm tags must start at 0 (t goes 1..4096): 2 parities x 2048 x 8B
    hipMemsetAsync(d_ws, 0, 2 * HID * sizeof(unsigned long long), stream);

    dim3 g1(HID / BN, T_STEPS / BM);        // (16, 32)
    gemm_u<<<g1, 256, 0, stream>>>(x, Wih, bih, bhh, out);
    cwrnn_rec<<<NWAVE, 64, 0, stream>>>(out, Whh, comm);
}